// Round 3
// baseline (721.233 us; speedup 1.0000x reference)
//
#include <hip/hip_runtime.h>

// ---------------------------------------------------------------------------
// 3-layer GAT (heads=1) forward. N=100000, E=1600000, Ep=E+N, G=128,
// ND=16, ED=2, H=32.
// R3: edge_enc colsum via wave64 shfl + 64-slot spread atomics (was 2-address
// contention, 162us); scatter writes one 16B record {src,f0,f1} per edge.
// ---------------------------------------------------------------------------

__global__ void k_node_enc(const float* __restrict__ nf, const float* __restrict__ W,
                           const float* __restrict__ b, float* __restrict__ x, int n) {
    int gid = blockIdx.x * 256 + threadIdx.x;
    if (gid >= n * 16) return;
    int node = gid >> 4, j = gid & 15;
    const float* xr = nf + node * 9;
    float acc = b[j];
#pragma unroll
    for (int k = 0; k < 9; ++k) acc += xr[k] * W[k * 16 + j];
    x[gid] = acc;
}

// colsum: 64 slot-pairs (128 floats), spread atomics; wave64 shfl reduce (no barriers)
__global__ void k_edge_enc(const float* __restrict__ ea, const float* __restrict__ W,
                           const float* __restrict__ b, float2* __restrict__ ef,
                           float* __restrict__ colsum, int e) {
    int gid = blockIdx.x * 256 + threadIdx.x;
    float f0 = 0.f, f1 = 0.f;
    if (gid < e) {
        const float* r = ea + (size_t)gid * 3;
        float a0 = r[0], a1 = r[1], a2 = r[2];
        f0 = a0 * W[0] + a1 * W[2] + a2 * W[4] + b[0];
        f1 = a0 * W[1] + a1 * W[3] + a2 * W[5] + b[1];
        ef[gid] = make_float2(f0, f1);
    }
#pragma unroll
    for (int off = 32; off > 0; off >>= 1) {
        f0 += __shfl_xor(f0, off, 64);
        f1 += __shfl_xor(f1, off, 64);
    }
    if ((threadIdx.x & 63) == 0) {
        int slot = ((blockIdx.x * 4 + (threadIdx.x >> 6)) & 63) * 2;
        atomicAdd(colsum + slot, f0);
        atomicAdd(colsum + slot + 1, f1);
    }
}

__global__ void k_deg(const int* __restrict__ dstE, int* __restrict__ deg, int e, int n) {
    int gid = blockIdx.x * 256 + threadIdx.x;
    if (gid >= e + n) return;
    int d = (gid < e) ? dstE[gid] : gid - e;
    atomicAdd(deg + d, 1);
}

__global__ void k_scan1(const int* __restrict__ deg, int* __restrict__ rp,
                        int* __restrict__ aux, int n) {
    __shared__ int s[256];
    int t = threadIdx.x, i = blockIdx.x * 256 + t;
    int v = (i < n) ? deg[i] : 0;
    s[t] = v; __syncthreads();
    for (int o = 1; o < 256; o <<= 1) {
        int x = (t >= o) ? s[t - o] : 0;
        __syncthreads();
        s[t] += x;
        __syncthreads();
    }
    if (i < n) rp[i] = s[t] - v;
    if (t == 255) aux[blockIdx.x] = s[255];
}

__global__ void k_scan2(int* __restrict__ aux, int nb) {
    __shared__ int s[512];
    int t = threadIdx.x;
    int v = (t < nb) ? aux[t] : 0;
    s[t] = v; __syncthreads();
    for (int o = 1; o < 512; o <<= 1) {
        int x = (t >= o) ? s[t - o] : 0;
        __syncthreads();
        s[t] += x;
        __syncthreads();
    }
    if (t < nb) aux[t] = s[t] - v;
}

__global__ void k_scan3(int* __restrict__ rp, const int* __restrict__ aux,
                        int* __restrict__ cursor, int n, int ep) {
    int i = blockIdx.x * 256 + threadIdx.x;
    if (i < n) {
        int v = rp[i] + aux[blockIdx.x];
        rp[i] = v;
        cursor[i] = v;
    }
    if (i == 0) rp[n] = ep;
}

// consts: [0..5] = (We@ae) per layer, [12..13] = self-loop ef mean fill
__global__ void k_consts(const float* __restrict__ We0, const float* __restrict__ ae0,
                         const float* __restrict__ We1, const float* __restrict__ ae1,
                         const float* __restrict__ We2, const float* __restrict__ ae2,
                         const float* __restrict__ colsum, float einv,
                         float* __restrict__ consts) {
    if (threadIdx.x != 0 || blockIdx.x != 0) return;
    float m0 = 0.f, m1 = 0.f;
    for (int k = 0; k < 64; ++k) { m0 += colsum[2 * k]; m1 += colsum[2 * k + 1]; }
    consts[12] = m0 * einv;
    consts[13] = m1 * einv;
    const float* We[3] = {We0, We1, We2};
    const float* ae[3] = {ae0, ae1, ae2};
    for (int l = 0; l < 3; ++l) {
        float c0 = 0.f, c1 = 0.f;
        for (int j = 0; j < 32; ++j) {
            c0 += We[l][j] * ae[l][j];
            c1 += We[l][32 + j] * ae[l][j];
        }
        consts[l * 2 + 0] = c0;
        consts[l * 2 + 1] = c1;
    }
}

// One scattered 16B record per CSR slot: {src, f0, f1, 0}
__global__ void k_scatter(const int* __restrict__ ei0, const int* __restrict__ ei1,
                          const float2* __restrict__ ef, const float* __restrict__ consts,
                          int* __restrict__ cursor, int4* __restrict__ recs,
                          int e, int n) {
    int gid = blockIdx.x * 256 + threadIdx.x;
    if (gid >= e + n) return;
    int s, d; float2 f;
    if (gid < e) {
        s = ei0[gid]; d = ei1[gid]; f = ef[gid];
    } else {
        s = d = gid - e;
        f = make_float2(consts[12], consts[13]);
    }
    int pos = atomicAdd(cursor + d, 1);
    int4 r;
    r.x = s;
    r.y = __float_as_int(f.x);
    r.z = __float_as_int(f.y);
    r.w = 0;
    recs[pos] = r;
}

template <int K>
__global__ void k_hproj(const float* __restrict__ x, const float* __restrict__ W,
                        const float* __restrict__ as_, const float* __restrict__ ad_,
                        float* __restrict__ h, float* __restrict__ asrc,
                        float* __restrict__ adst, int n) {
    __shared__ float sW[K * 32];
    for (int i = threadIdx.x; i < K * 32; i += 256) sW[i] = W[i];
    __syncthreads();
    int node = blockIdx.x * 8 + (threadIdx.x >> 5);
    int j = threadIdx.x & 31;
    if (node >= n) return;
    const float* xr = x + (size_t)node * K;
    float acc = 0.f;
#pragma unroll
    for (int k = 0; k < K; ++k) acc += xr[k] * sW[k * 32 + j];
    h[(size_t)node * 32 + j] = acc;
    float r1 = acc * as_[j], r2 = acc * ad_[j];
    for (int off = 16; off > 0; off >>= 1) {
        r1 += __shfl_xor(r1, off, 32);
        r2 += __shfl_xor(r2, off, 32);
    }
    if (j == 0) { asrc[node] = r1; adst[node] = r2; }
}

// Fused edge-softmax + aggregation. One 32-lane group per dst node.
__global__ void k_agg(const int* __restrict__ rp, const int4* __restrict__ recs,
                      const float* __restrict__ asrc, const float* __restrict__ adst,
                      const float* __restrict__ consts, const float* __restrict__ h,
                      const float* __restrict__ bb, float* __restrict__ xout,
                      int n, int layer) {
    int node = blockIdx.x * 8 + (threadIdx.x >> 5);
    int j = threadIdx.x & 31;
    if (node >= n) return;
    float c0 = consts[layer * 2], c1 = consts[layer * 2 + 1];
    int r0 = rp[node], r1 = rp[node + 1];
    float adn = adst[node];
    float acc = 0.f, psum = 0.f;
    for (int c = r0; c < r1; c += 32) {
        int i = c + j;
        float pe = 0.f; int s = 0;
        if (i < r1) {
            int4 r = recs[i];
            s = r.x;
            float lg = asrc[s] + adn
                     + __int_as_float(r.y) * c0 + __int_as_float(r.z) * c1;
            lg = lg > 0.f ? lg : 0.2f * lg;
            pe = __expf(lg);
        }
        psum += pe;
        int cnt = min(32, r1 - c);
        int t = 0;
        for (; t + 4 <= cnt; t += 4) {
            int s0 = __shfl(s, t, 32), s1 = __shfl(s, t + 1, 32);
            int s2 = __shfl(s, t + 2, 32), s3 = __shfl(s, t + 3, 32);
            float p0 = __shfl(pe, t, 32), p1 = __shfl(pe, t + 1, 32);
            float p2 = __shfl(pe, t + 2, 32), p3 = __shfl(pe, t + 3, 32);
            float h0 = h[(size_t)s0 * 32 + j];
            float h1 = h[(size_t)s1 * 32 + j];
            float h2 = h[(size_t)s2 * 32 + j];
            float h3 = h[(size_t)s3 * 32 + j];
            acc += p0 * h0; acc += p1 * h1; acc += p2 * h2; acc += p3 * h3;
        }
        for (; t < cnt; ++t) {
            int st = __shfl(s, t, 32);
            float pt = __shfl(pe, t, 32);
            acc += pt * h[(size_t)st * 32 + j];
        }
    }
    for (int off = 16; off > 0; off >>= 1) psum += __shfl_xor(psum, off, 32);
    xout[(size_t)node * 32 + j] = acc / (psum + 1e-16f) + bb[j];
}

__global__ void k_bounds(const int* __restrict__ batch, int* __restrict__ bounds,
                         int n, int g) {
    int t = blockIdx.x * 256 + threadIdx.x;
    if (t > g) return;
    if (t == g) { bounds[g] = n; return; }
    int lo = 0, hi = n;
    while (lo < hi) {
        int mid = (lo + hi) >> 1;
        if (batch[mid] < t) lo = mid + 1; else hi = mid;
    }
    bounds[t] = lo;
}

// out[g] = (1/cnt_g) * sum_{n in g} (x_cat[n] . W_l3) + b  -- commuted readout.
__global__ void k_dot(const float* __restrict__ x1, const float* __restrict__ x2,
                      const float* __restrict__ x3, const int* __restrict__ batch,
                      const float* __restrict__ Wl3, float* __restrict__ gsum, int n) {
    int node = blockIdx.x * 8 + (threadIdx.x >> 5);
    int j = threadIdx.x & 31;
    if (node >= n) return;
    size_t o = (size_t)node * 32 + j;
    float v = x1[o] * Wl3[j] + x2[o] * Wl3[32 + j] + x3[o] * Wl3[64 + j];
    for (int off = 16; off > 0; off >>= 1) v += __shfl_xor(v, off, 32);
    if (j == 0) atomicAdd(gsum + (size_t)batch[node] * 32 + (blockIdx.x & 31), v);
}

__global__ void k_out(const float* __restrict__ gsum, const int* __restrict__ bounds,
                      const float* __restrict__ bl3, float* __restrict__ out, int g) {
    int t = threadIdx.x;
    if (t >= g) return;
    float acc = 0.f;
    for (int k = 0; k < 32; ++k) acc += gsum[(size_t)t * 32 + k];
    float cnt = (float)(bounds[t + 1] - bounds[t]);
    out[t] = acc / fmaxf(cnt, 1.f) + bl3[0];
}

extern "C" void kernel_launch(void* const* d_in, const int* in_sizes, int n_in,
                              void* d_out, int out_size, void* d_ws, size_t ws_size,
                              hipStream_t stream) {
    (void)n_in; (void)out_size; (void)ws_size;
    const float* nf    = (const float*)d_in[0];
    const int*   ei    = (const int*)d_in[1];
    const float* ea    = (const float*)d_in[2];
    const int*   batch = (const int*)d_in[3];
    const float* W_ne  = (const float*)d_in[4];
    const float* b_ne  = (const float*)d_in[5];
    const float* W_ee  = (const float*)d_in[6];
    const float* b_ee  = (const float*)d_in[7];
    const float* W_l3  = (const float*)d_in[8];
    const float* b_l3  = (const float*)d_in[9];
    const float *Wl[3], *asl[3], *adl[3], *Wel[3], *ael[3], *bbl[3];
    for (int l = 0; l < 3; ++l) {
        Wl[l]  = (const float*)d_in[10 + 6 * l];
        asl[l] = (const float*)d_in[11 + 6 * l];
        adl[l] = (const float*)d_in[12 + 6 * l];
        Wel[l] = (const float*)d_in[13 + 6 * l];
        ael[l] = (const float*)d_in[14 + 6 * l];
        bbl[l] = (const float*)d_in[15 + 6 * l];
    }

    const int n  = in_sizes[3];        // 100000
    const int e  = in_sizes[2] / 3;    // 1600000
    const int ep = e + n;
    const int* ei0 = ei;
    const int* ei1 = ei + e;

    char* w = (char*)d_ws;
    size_t off = 0;
    auto alloc = [&](size_t b) { size_t o = off; off = (off + b + 255) & ~(size_t)255; return o; };
    float*  x0     = (float*)(w + alloc((size_t)n * 16 * 4));
    float*  x1     = (float*)(w + alloc((size_t)n * 32 * 4));
    float*  x2     = (float*)(w + alloc((size_t)n * 32 * 4));
    float*  x3     = (float*)(w + alloc((size_t)n * 32 * 4));
    float*  h      = (float*)(w + alloc((size_t)n * 32 * 4));
    float*  asrc   = (float*)(w + alloc((size_t)n * 4));
    float*  adst   = (float*)(w + alloc((size_t)n * 4));
    float*  ef     = (float*)(w + alloc((size_t)e * 2 * 4));
    int4*   recs   = (int4*)(w + alloc((size_t)ep * 16));
    int*    deg    = (int*)(w + alloc((size_t)n * 4));
    int*    rp     = (int*)(w + alloc((size_t)(n + 1) * 4));
    int*    cursor = (int*)(w + alloc((size_t)n * 4));
    int*    aux    = (int*)(w + alloc(512 * 4));
    float*  colsum = (float*)(w + alloc(128 * 4));
    float*  consts = (float*)(w + alloc(256));
    int*    bounds = (int*)(w + alloc(129 * 4));
    float*  gsum   = (float*)(w + alloc((size_t)128 * 32 * 4));

    hipMemsetAsync(deg, 0, (size_t)n * 4, stream);
    hipMemsetAsync(colsum, 0, 128 * 4, stream);
    hipMemsetAsync(gsum, 0, (size_t)128 * 32 * 4, stream);

    k_node_enc<<<(n * 16 + 255) / 256, 256, 0, stream>>>(nf, W_ne, b_ne, x0, n);
    k_edge_enc<<<(e + 255) / 256, 256, 0, stream>>>(ea, W_ee, b_ee, (float2*)ef, colsum, e);
    k_consts<<<1, 64, 0, stream>>>(Wel[0], ael[0], Wel[1], ael[1], Wel[2], ael[2],
                                   colsum, 1.0f / (float)e, consts);
    k_deg<<<(ep + 255) / 256, 256, 0, stream>>>(ei1, deg, e, n);
    int nb = (n + 255) / 256;
    k_scan1<<<nb, 256, 0, stream>>>(deg, rp, aux, n);
    k_scan2<<<1, 512, 0, stream>>>(aux, nb);
    k_scan3<<<nb, 256, 0, stream>>>(rp, aux, cursor, n, ep);
    k_scatter<<<(ep + 255) / 256, 256, 0, stream>>>(ei0, ei1, (const float2*)ef, consts,
                                                    cursor, recs, e, n);
    k_bounds<<<1, 256, 0, stream>>>(batch, bounds, n, 128);

    const float* xin = x0;
    float* xo[3] = {x1, x2, x3};
    for (int l = 0; l < 3; ++l) {
        if (l == 0)
            k_hproj<16><<<(n + 7) / 8, 256, 0, stream>>>(xin, Wl[l], asl[l], adl[l],
                                                         h, asrc, adst, n);
        else
            k_hproj<32><<<(n + 7) / 8, 256, 0, stream>>>(xin, Wl[l], asl[l], adl[l],
                                                         h, asrc, adst, n);
        k_agg<<<(n + 7) / 8, 256, 0, stream>>>(rp, recs, asrc, adst, consts,
                                               h, bbl[l], xo[l], n, l);
        xin = xo[l];
    }
    k_dot<<<(n + 7) / 8, 256, 0, stream>>>(x1, x2, x3, batch, W_l3, gsum, n);
    k_out<<<1, 128, 0, stream>>>(gsum, bounds, b_l3, (float*)d_out, 128);
}

// Round 4
// 544.887 us; speedup vs baseline: 1.3236x; 1.3236x over previous
//
#include <hip/hip_runtime.h>

// ---------------------------------------------------------------------------
// 3-layer GAT (heads=1) forward. N=100000, E=1600000, Ep=E+N, G=128,
// ND=16, ED=2, H=32.
// R4: k_edge_enc colsum atomics removed entirely (per-wave partials to unique
// slots -> parallel reduce in k_consts). R3's lesson: spreading atomics over
// 512B (~2 L2 channels) didn't help; same-channel TCC atomic RMWs serialize
// (~7ns each * 25-50K = the whole 162-184us). Also 4 edges/thread float4 I/O.
// ---------------------------------------------------------------------------

__global__ void k_node_enc(const float* __restrict__ nf, const float* __restrict__ W,
                           const float* __restrict__ b, float* __restrict__ x, int n) {
    int gid = blockIdx.x * 256 + threadIdx.x;
    if (gid >= n * 16) return;
    int node = gid >> 4, j = gid & 15;
    const float* xr = nf + node * 9;
    float acc = b[j];
#pragma unroll
    for (int k = 0; k < 9; ++k) acc += xr[k] * W[k * 16 + j];
    x[gid] = acc;
}

// 4 edges/thread: 3 float4 loads, 2 float4 stores. Per-wave partial colsum
// written to a UNIQUE slot (no atomics anywhere).
__global__ void k_edge_enc(const float4* __restrict__ ea4, const float* __restrict__ W,
                           const float* __restrict__ b, float4* __restrict__ ef4,
                           float2* __restrict__ partial, int e) {
    int tid = blockIdx.x * 256 + threadIdx.x;
    int e4 = e >> 2;  // e divisible by 4 here (1.6M)
    float s0 = 0.f, s1 = 0.f;
    if (tid < e4) {
        float4 q0 = ea4[tid * 3], q1 = ea4[tid * 3 + 1], q2 = ea4[tid * 3 + 2];
        float w00 = W[0], w10 = W[2], w20 = W[4];
        float w01 = W[1], w11 = W[3], w21 = W[5];
        float b0 = b[0], b1 = b[1];
        float f00 = q0.x * w00 + q0.y * w10 + q0.z * w20 + b0;
        float f01 = q0.x * w01 + q0.y * w11 + q0.z * w21 + b1;
        float f10 = q0.w * w00 + q1.x * w10 + q1.y * w20 + b0;
        float f11 = q0.w * w01 + q1.x * w11 + q1.y * w21 + b1;
        float f20 = q1.z * w00 + q1.w * w10 + q2.x * w20 + b0;
        float f21 = q1.z * w01 + q1.w * w11 + q2.x * w21 + b1;
        float f30 = q2.y * w00 + q2.z * w10 + q2.w * w20 + b0;
        float f31 = q2.y * w01 + q2.z * w11 + q2.w * w21 + b1;
        ef4[tid * 2]     = make_float4(f00, f01, f10, f11);
        ef4[tid * 2 + 1] = make_float4(f20, f21, f30, f31);
        s0 = f00 + f10 + f20 + f30;
        s1 = f01 + f11 + f21 + f31;
    }
#pragma unroll
    for (int off = 32; off > 0; off >>= 1) {
        s0 += __shfl_xor(s0, off, 64);
        s1 += __shfl_xor(s1, off, 64);
    }
    if ((threadIdx.x & 63) == 0)
        partial[(blockIdx.x << 2) + (threadIdx.x >> 6)] = make_float2(s0, s1);
}

__global__ void k_deg(const int* __restrict__ dstE, int* __restrict__ deg, int e, int n) {
    int gid = blockIdx.x * 256 + threadIdx.x;
    if (gid >= e + n) return;
    int d = (gid < e) ? dstE[gid] : gid - e;
    atomicAdd(deg + d, 1);
}

__global__ void k_scan1(const int* __restrict__ deg, int* __restrict__ rp,
                        int* __restrict__ aux, int n) {
    __shared__ int s[256];
    int t = threadIdx.x, i = blockIdx.x * 256 + t;
    int v = (i < n) ? deg[i] : 0;
    s[t] = v; __syncthreads();
    for (int o = 1; o < 256; o <<= 1) {
        int x = (t >= o) ? s[t - o] : 0;
        __syncthreads();
        s[t] += x;
        __syncthreads();
    }
    if (i < n) rp[i] = s[t] - v;
    if (t == 255) aux[blockIdx.x] = s[255];
}

__global__ void k_scan2(int* __restrict__ aux, int nb) {
    __shared__ int s[512];
    int t = threadIdx.x;
    int v = (t < nb) ? aux[t] : 0;
    s[t] = v; __syncthreads();
    for (int o = 1; o < 512; o <<= 1) {
        int x = (t >= o) ? s[t - o] : 0;
        __syncthreads();
        s[t] += x;
        __syncthreads();
    }
    if (t < nb) aux[t] = s[t] - v;
}

__global__ void k_scan3(int* __restrict__ rp, const int* __restrict__ aux,
                        int* __restrict__ cursor, int n, int ep) {
    int i = blockIdx.x * 256 + threadIdx.x;
    if (i < n) {
        int v = rp[i] + aux[blockIdx.x];
        rp[i] = v;
        cursor[i] = v;
    }
    if (i == 0) rp[n] = ep;
}

// Reduce per-wave colsum partials; consts: [0..5]=(We@ae) per layer,
// [12..13]=self-loop mean fill.
__global__ void k_consts(const float* __restrict__ We0, const float* __restrict__ ae0,
                         const float* __restrict__ We1, const float* __restrict__ ae1,
                         const float* __restrict__ We2, const float* __restrict__ ae2,
                         const float2* __restrict__ partial, int nw, float einv,
                         float* __restrict__ consts) {
    __shared__ float r0[256], r1[256];
    int t = threadIdx.x;
    float m0 = 0.f, m1 = 0.f;
    for (int i = t; i < nw; i += 256) {
        float2 v = partial[i];
        m0 += v.x; m1 += v.y;
    }
    r0[t] = m0; r1[t] = m1;
    __syncthreads();
    for (int o = 128; o > 0; o >>= 1) {
        if (t < o) { r0[t] += r0[t + o]; r1[t] += r1[t + o]; }
        __syncthreads();
    }
    if (t == 0) {
        consts[12] = r0[0] * einv;
        consts[13] = r1[0] * einv;
        const float* We[3] = {We0, We1, We2};
        const float* ae[3] = {ae0, ae1, ae2};
        for (int l = 0; l < 3; ++l) {
            float c0 = 0.f, c1 = 0.f;
            for (int j = 0; j < 32; ++j) {
                c0 += We[l][j] * ae[l][j];
                c1 += We[l][32 + j] * ae[l][j];
            }
            consts[l * 2 + 0] = c0;
            consts[l * 2 + 1] = c1;
        }
    }
}

// One scattered 16B record per CSR slot: {src, f0, f1, 0}
__global__ void k_scatter(const int* __restrict__ ei0, const int* __restrict__ ei1,
                          const float2* __restrict__ ef, const float* __restrict__ consts,
                          int* __restrict__ cursor, int4* __restrict__ recs,
                          int e, int n) {
    int gid = blockIdx.x * 256 + threadIdx.x;
    if (gid >= e + n) return;
    int s, d; float2 f;
    if (gid < e) {
        s = ei0[gid]; d = ei1[gid]; f = ef[gid];
    } else {
        s = d = gid - e;
        f = make_float2(consts[12], consts[13]);
    }
    int pos = atomicAdd(cursor + d, 1);
    int4 r;
    r.x = s;
    r.y = __float_as_int(f.x);
    r.z = __float_as_int(f.y);
    r.w = 0;
    recs[pos] = r;
}

template <int K>
__global__ void k_hproj(const float* __restrict__ x, const float* __restrict__ W,
                        const float* __restrict__ as_, const float* __restrict__ ad_,
                        float* __restrict__ h, float* __restrict__ asrc,
                        float* __restrict__ adst, int n) {
    __shared__ float sW[K * 32];
    for (int i = threadIdx.x; i < K * 32; i += 256) sW[i] = W[i];
    __syncthreads();
    int node = blockIdx.x * 8 + (threadIdx.x >> 5);
    int j = threadIdx.x & 31;
    if (node >= n) return;
    const float* xr = x + (size_t)node * K;
    float acc = 0.f;
#pragma unroll
    for (int k = 0; k < K; ++k) acc += xr[k] * sW[k * 32 + j];
    h[(size_t)node * 32 + j] = acc;
    float r1 = acc * as_[j], r2 = acc * ad_[j];
    for (int off = 16; off > 0; off >>= 1) {
        r1 += __shfl_xor(r1, off, 32);
        r2 += __shfl_xor(r2, off, 32);
    }
    if (j == 0) { asrc[node] = r1; adst[node] = r2; }
}

// Fused edge-softmax + aggregation. One 32-lane group per dst node.
__global__ void k_agg(const int* __restrict__ rp, const int4* __restrict__ recs,
                      const float* __restrict__ asrc, const float* __restrict__ adst,
                      const float* __restrict__ consts, const float* __restrict__ h,
                      const float* __restrict__ bb, float* __restrict__ xout,
                      int n, int layer) {
    int node = blockIdx.x * 8 + (threadIdx.x >> 5);
    int j = threadIdx.x & 31;
    if (node >= n) return;
    float c0 = consts[layer * 2], c1 = consts[layer * 2 + 1];
    int r0 = rp[node], r1 = rp[node + 1];
    float adn = adst[node];
    float acc = 0.f, psum = 0.f;
    for (int c = r0; c < r1; c += 32) {
        int i = c + j;
        float pe = 0.f; int s = 0;
        if (i < r1) {
            int4 r = recs[i];
            s = r.x;
            float lg = asrc[s] + adn
                     + __int_as_float(r.y) * c0 + __int_as_float(r.z) * c1;
            lg = lg > 0.f ? lg : 0.2f * lg;
            pe = __expf(lg);
        }
        psum += pe;
        int cnt = min(32, r1 - c);
        int t = 0;
        for (; t + 4 <= cnt; t += 4) {
            int s0 = __shfl(s, t, 32), s1 = __shfl(s, t + 1, 32);
            int s2 = __shfl(s, t + 2, 32), s3 = __shfl(s, t + 3, 32);
            float p0 = __shfl(pe, t, 32), p1 = __shfl(pe, t + 1, 32);
            float p2 = __shfl(pe, t + 2, 32), p3 = __shfl(pe, t + 3, 32);
            float h0 = h[(size_t)s0 * 32 + j];
            float h1 = h[(size_t)s1 * 32 + j];
            float h2 = h[(size_t)s2 * 32 + j];
            float h3 = h[(size_t)s3 * 32 + j];
            acc += p0 * h0; acc += p1 * h1; acc += p2 * h2; acc += p3 * h3;
        }
        for (; t < cnt; ++t) {
            int st = __shfl(s, t, 32);
            float pt = __shfl(pe, t, 32);
            acc += pt * h[(size_t)st * 32 + j];
        }
    }
    for (int off = 16; off > 0; off >>= 1) psum += __shfl_xor(psum, off, 32);
    xout[(size_t)node * 32 + j] = acc / (psum + 1e-16f) + bb[j];
}

__global__ void k_bounds(const int* __restrict__ batch, int* __restrict__ bounds,
                         int n, int g) {
    int t = blockIdx.x * 256 + threadIdx.x;
    if (t > g) return;
    if (t == g) { bounds[g] = n; return; }
    int lo = 0, hi = n;
    while (lo < hi) {
        int mid = (lo + hi) >> 1;
        if (batch[mid] < t) lo = mid + 1; else hi = mid;
    }
    bounds[t] = lo;
}

// out[g] = (1/cnt_g) * sum_{n in g} (x_cat[n] . W_l3) + b  -- commuted readout.
__global__ void k_dot(const float* __restrict__ x1, const float* __restrict__ x2,
                      const float* __restrict__ x3, const int* __restrict__ batch,
                      const float* __restrict__ Wl3, float* __restrict__ gsum, int n) {
    int node = blockIdx.x * 8 + (threadIdx.x >> 5);
    int j = threadIdx.x & 31;
    if (node >= n) return;
    size_t o = (size_t)node * 32 + j;
    float v = x1[o] * Wl3[j] + x2[o] * Wl3[32 + j] + x3[o] * Wl3[64 + j];
    for (int off = 16; off > 0; off >>= 1) v += __shfl_xor(v, off, 32);
    if (j == 0) atomicAdd(gsum + (size_t)batch[node] * 32 + (blockIdx.x & 31), v);
}

__global__ void k_out(const float* __restrict__ gsum, const int* __restrict__ bounds,
                      const float* __restrict__ bl3, float* __restrict__ out, int g) {
    int t = threadIdx.x;
    if (t >= g) return;
    float acc = 0.f;
    for (int k = 0; k < 32; ++k) acc += gsum[(size_t)t * 32 + k];
    float cnt = (float)(bounds[t + 1] - bounds[t]);
    out[t] = acc / fmaxf(cnt, 1.f) + bl3[0];
}

extern "C" void kernel_launch(void* const* d_in, const int* in_sizes, int n_in,
                              void* d_out, int out_size, void* d_ws, size_t ws_size,
                              hipStream_t stream) {
    (void)n_in; (void)out_size; (void)ws_size;
    const float* nf    = (const float*)d_in[0];
    const int*   ei    = (const int*)d_in[1];
    const float* ea    = (const float*)d_in[2];
    const int*   batch = (const int*)d_in[3];
    const float* W_ne  = (const float*)d_in[4];
    const float* b_ne  = (const float*)d_in[5];
    const float* W_ee  = (const float*)d_in[6];
    const float* b_ee  = (const float*)d_in[7];
    const float* W_l3  = (const float*)d_in[8];
    const float* b_l3  = (const float*)d_in[9];
    const float *Wl[3], *asl[3], *adl[3], *Wel[3], *ael[3], *bbl[3];
    for (int l = 0; l < 3; ++l) {
        Wl[l]  = (const float*)d_in[10 + 6 * l];
        asl[l] = (const float*)d_in[11 + 6 * l];
        adl[l] = (const float*)d_in[12 + 6 * l];
        Wel[l] = (const float*)d_in[13 + 6 * l];
        ael[l] = (const float*)d_in[14 + 6 * l];
        bbl[l] = (const float*)d_in[15 + 6 * l];
    }

    const int n  = in_sizes[3];        // 100000
    const int e  = in_sizes[2] / 3;    // 1600000
    const int ep = e + n;
    const int* ei0 = ei;
    const int* ei1 = ei + e;

    char* w = (char*)d_ws;
    size_t off = 0;
    auto alloc = [&](size_t b) { size_t o = off; off = (off + b + 255) & ~(size_t)255; return o; };
    float*  x0      = (float*)(w + alloc((size_t)n * 16 * 4));
    float*  x1      = (float*)(w + alloc((size_t)n * 32 * 4));
    float*  x2      = (float*)(w + alloc((size_t)n * 32 * 4));
    float*  x3      = (float*)(w + alloc((size_t)n * 32 * 4));
    float*  h       = (float*)(w + alloc((size_t)n * 32 * 4));
    float*  asrc    = (float*)(w + alloc((size_t)n * 4));
    float*  adst    = (float*)(w + alloc((size_t)n * 4));
    float*  ef      = (float*)(w + alloc((size_t)e * 2 * 4));
    int4*   recs    = (int4*)(w + alloc((size_t)ep * 16));
    int*    deg     = (int*)(w + alloc((size_t)n * 4));
    int*    rp      = (int*)(w + alloc((size_t)(n + 1) * 4));
    int*    cursor  = (int*)(w + alloc((size_t)n * 4));
    int*    aux     = (int*)(w + alloc(512 * 4));
    float2* partial = (float2*)(w + alloc((size_t)8192 * 8));
    float*  consts  = (float*)(w + alloc(256));
    int*    bounds  = (int*)(w + alloc(129 * 4));
    float*  gsum    = (float*)(w + alloc((size_t)128 * 32 * 4));

    hipMemsetAsync(deg, 0, (size_t)n * 4, stream);
    hipMemsetAsync(gsum, 0, (size_t)128 * 32 * 4, stream);

    int e4 = e >> 2;                       // 400000
    int nbe = (e4 + 255) / 256;            // 1563
    int nw  = nbe * 4;                     // per-wave partial slots

    k_node_enc<<<(n * 16 + 255) / 256, 256, 0, stream>>>(nf, W_ne, b_ne, x0, n);
    k_edge_enc<<<nbe, 256, 0, stream>>>((const float4*)ea, W_ee, b_ee,
                                        (float4*)ef, partial, e);
    k_consts<<<1, 256, 0, stream>>>(Wel[0], ael[0], Wel[1], ael[1], Wel[2], ael[2],
                                    partial, nw, 1.0f / (float)e, consts);
    k_deg<<<(ep + 255) / 256, 256, 0, stream>>>(ei1, deg, e, n);
    int nb = (n + 255) / 256;
    k_scan1<<<nb, 256, 0, stream>>>(deg, rp, aux, n);
    k_scan2<<<1, 512, 0, stream>>>(aux, nb);
    k_scan3<<<nb, 256, 0, stream>>>(rp, aux, cursor, n, ep);
    k_scatter<<<(ep + 255) / 256, 256, 0, stream>>>(ei0, ei1, (const float2*)ef, consts,
                                                    cursor, recs, e, n);
    k_bounds<<<1, 256, 0, stream>>>(batch, bounds, n, 128);

    const float* xin = x0;
    float* xo[3] = {x1, x2, x3};
    for (int l = 0; l < 3; ++l) {
        if (l == 0)
            k_hproj<16><<<(n + 7) / 8, 256, 0, stream>>>(xin, Wl[l], asl[l], adl[l],
                                                         h, asrc, adst, n);
        else
            k_hproj<32><<<(n + 7) / 8, 256, 0, stream>>>(xin, Wl[l], asl[l], adl[l],
                                                         h, asrc, adst, n);
        k_agg<<<(n + 7) / 8, 256, 0, stream>>>(rp, recs, asrc, adst, consts,
                                               h, bbl[l], xo[l], n, l);
        xin = xo[l];
    }
    k_dot<<<(n + 7) / 8, 256, 0, stream>>>(x1, x2, x3, batch, W_l3, gsum, n);
    k_out<<<1, 128, 0, stream>>>(gsum, bounds, b_l3, (float*)d_out, 128);
}

// Round 5
// 482.189 us; speedup vs baseline: 1.4957x; 1.1300x over previous
//
#include <hip/hip_runtime.h>
#include <hip/hip_fp16.h>

// ---------------------------------------------------------------------------
// 3-layer GAT (heads=1) forward. N=100000, E=1600000, Ep=E+N, G=128,
// ND=16, ED=2, H=32.
// R5: CSR build via 2-phase bucket sort (bucket = dst>>9, 196 buckets).
//   A: per-block LDS hist -> 196 global counters        (kills k_deg's RMWs)
//   B: 4096-edge blocks reserve per-bucket runs, write 8B staging recs
//      {src<<9|dstloc, half2(f0,f1)} -- same-block stores share L2 lines
//   C: one block/bucket: LDS node-hist+scan -> coalesced rp (kills scans),
//      place final srcs[] + aed0/1/2[] (per-layer edge-logit scalar) within
//      the bucket's ~140KB region (single-XCD L2 locality).
// R4 lesson: random 16B scatter = 64B writeback per store (105MB for 27MB).
// ---------------------------------------------------------------------------

#define NBUCK_MAX 256

__global__ void k_node_enc(const float* __restrict__ nf, const float* __restrict__ W,
                           const float* __restrict__ b, float* __restrict__ x, int n) {
    int gid = blockIdx.x * 256 + threadIdx.x;
    if (gid >= n * 16) return;
    int node = gid >> 4, j = gid & 15;
    const float* xr = nf + node * 9;
    float acc = b[j];
#pragma unroll
    for (int k = 0; k < 9; ++k) acc += xr[k] * W[k * 16 + j];
    x[gid] = acc;
}

// Column sums of ef = ea@W_ee + b_ee (for the self-loop mean fill), without
// materializing ef. 4 edges/thread float4 loads; per-wave partial to a
// unique slot (no atomics).
__global__ void k_colsum(const float4* __restrict__ ea4, const float* __restrict__ W,
                         const float* __restrict__ b, float2* __restrict__ partial, int e) {
    int tid = blockIdx.x * 256 + threadIdx.x;
    int e4 = e >> 2;
    float s0 = 0.f, s1 = 0.f;
    if (tid < e4) {
        float4 q0 = ea4[tid * 3], q1 = ea4[tid * 3 + 1], q2 = ea4[tid * 3 + 2];
        float w00 = W[0], w10 = W[2], w20 = W[4];
        float w01 = W[1], w11 = W[3], w21 = W[5];
        s0 = (q0.x + q0.w + q1.z + q2.y) * w00
           + (q0.y + q1.x + q1.w + q2.z) * w10
           + (q0.z + q1.y + q2.x + q2.w) * w20 + 4.f * b[0];
        s1 = (q0.x + q0.w + q1.z + q2.y) * w01
           + (q0.y + q1.x + q1.w + q2.z) * w11
           + (q0.z + q1.y + q2.x + q2.w) * w21 + 4.f * b[1];
    }
#pragma unroll
    for (int off = 32; off > 0; off >>= 1) {
        s0 += __shfl_xor(s0, off, 64);
        s1 += __shfl_xor(s1, off, 64);
    }
    if ((threadIdx.x & 63) == 0)
        partial[(blockIdx.x << 2) + (threadIdx.x >> 6)] = make_float2(s0, s1);
}

// consts: [0..5]=(We@ae) per layer, [12..13]=self-loop mean fill
__global__ void k_consts(const float* __restrict__ We0, const float* __restrict__ ae0,
                         const float* __restrict__ We1, const float* __restrict__ ae1,
                         const float* __restrict__ We2, const float* __restrict__ ae2,
                         const float2* __restrict__ partial, int nw, float einv,
                         float* __restrict__ consts) {
    __shared__ float r0[256], r1[256];
    int t = threadIdx.x;
    float m0 = 0.f, m1 = 0.f;
    for (int i = t; i < nw; i += 256) {
        float2 v = partial[i];
        m0 += v.x; m1 += v.y;
    }
    r0[t] = m0; r1[t] = m1;
    __syncthreads();
    for (int o = 128; o > 0; o >>= 1) {
        if (t < o) { r0[t] += r0[t + o]; r1[t] += r1[t + o]; }
        __syncthreads();
    }
    if (t == 0) {
        consts[12] = r0[0] * einv;
        consts[13] = r1[0] * einv;
        const float* We[3] = {We0, We1, We2};
        const float* ae[3] = {ae0, ae1, ae2};
        for (int l = 0; l < 3; ++l) {
            float c0 = 0.f, c1 = 0.f;
            for (int j = 0; j < 32; ++j) {
                c0 += We[l][j] * ae[l][j];
                c1 += We[l][32 + j] * ae[l][j];
            }
            consts[l * 2 + 0] = c0;
            consts[l * 2 + 1] = c1;
        }
    }
}

// Phase A: bucket histogram (bucket = dst>>9). 4096 edges/block.
__global__ void k_hist(const int* __restrict__ ei1, int* __restrict__ bucket_cnt,
                       int e, int ep) {
    __shared__ int lh[NBUCK_MAX];
    int t = threadIdx.x;
    lh[t] = 0;
    __syncthreads();
    int base = blockIdx.x * 4096;
#pragma unroll
    for (int i = 0; i < 16; ++i) {
        int gid = base + i * 256 + t;
        if (gid < ep) {
            int d = (gid < e) ? ei1[gid] : gid - e;
            atomicAdd(&lh[d >> 9], 1);
        }
    }
    __syncthreads();
    if (lh[t]) atomicAdd(&bucket_cnt[t], lh[t]);
}

// Exclusive scan of bucket counts -> bases + cursor init.
__global__ void k_bbase(const int* __restrict__ bucket_cnt, int* __restrict__ bucket_base,
                        int* __restrict__ bcursor, int nbuck, int ep,
                        int* __restrict__ rp, int n) {
    __shared__ int s[256];
    int t = threadIdx.x;
    int v = (t < nbuck) ? bucket_cnt[t] : 0;
    s[t] = v;
    __syncthreads();
    for (int o = 1; o < 256; o <<= 1) {
        int x = (t >= o) ? s[t - o] : 0;
        __syncthreads();
        s[t] += x;
        __syncthreads();
    }
    int ex = s[t] - v;
    if (t < nbuck) { bucket_base[t] = ex; bcursor[t] = ex; }
    if (t == 0) { bucket_base[nbuck] = ep; rp[n] = ep; }
}

// Phase B: stage edges grouped by bucket. 4096 edges/block in registers;
// one run-reservation atomic per (block,bucket); staged rec = 8B:
// {src<<9|dstloc, half2(f0,f1)}.
__global__ void k_binB(const int* __restrict__ ei0, const int* __restrict__ ei1,
                       const float* __restrict__ ea, const float* __restrict__ We,
                       const float* __restrict__ be, const float* __restrict__ consts,
                       int* __restrict__ bcursor, unsigned int* __restrict__ sd_st,
                       unsigned int* __restrict__ fh_st, int e, int ep) {
    __shared__ int lh[NBUCK_MAX], lcur[NBUCK_MAX];
    int t = threadIdx.x;
    lh[t] = 0;
    __syncthreads();
    int base = blockIdx.x * 4096;
    unsigned int sd[16], fh[16];
    int bk[16];
    float w00 = We[0], w10 = We[2], w20 = We[4];
    float w01 = We[1], w11 = We[3], w21 = We[5];
    float b0 = be[0], b1 = be[1];
#pragma unroll
    for (int i = 0; i < 16; ++i) {
        int gid = base + i * 256 + t;
        bk[i] = -1;
        if (gid < ep) {
            int s, d; float f0, f1;
            if (gid < e) {
                s = ei0[gid]; d = ei1[gid];
                const float* r = ea + (size_t)gid * 3;
                float a0 = r[0], a1 = r[1], a2 = r[2];
                f0 = a0 * w00 + a1 * w10 + a2 * w20 + b0;
                f1 = a0 * w01 + a1 * w11 + a2 * w21 + b1;
            } else {
                s = d = gid - e;
                f0 = consts[12]; f1 = consts[13];
            }
            bk[i] = d >> 9;
            sd[i] = ((unsigned int)s << 9) | (unsigned int)(d & 511);
            __half2 hh = __floats2half2_rn(f0, f1);
            fh[i] = *reinterpret_cast<unsigned int*>(&hh);
            atomicAdd(&lh[bk[i]], 1);
        }
    }
    __syncthreads();
    if (lh[t] > 0) lcur[t] = atomicAdd(&bcursor[t], lh[t]);
    __syncthreads();
#pragma unroll
    for (int i = 0; i < 16; ++i) {
        if (bk[i] >= 0) {
            int pos = atomicAdd(&lcur[bk[i]], 1);
            sd_st[pos] = sd[i];
            fh_st[pos] = fh[i];
        }
    }
}

// Phase C: one block per bucket. LDS node-hist + scan -> rp (coalesced) and
// final CSR arrays srcs[], aed0/1/2[] (per-layer edge-logit scalar), all
// writes confined to this bucket's region.
__global__ void __launch_bounds__(1024)
k_binC(const unsigned int* __restrict__ sd_st, const unsigned int* __restrict__ fh_st,
       const int* __restrict__ bucket_base, const float* __restrict__ consts,
       int* __restrict__ rp, int* __restrict__ srcs, float* __restrict__ aed0,
       float* __restrict__ aed1, float* __restrict__ aed2, int n) {
    __shared__ int nh[512], ns[512];
    int k = blockIdx.x, t = threadIdx.x;
    int s0 = bucket_base[k], s1 = bucket_base[k + 1];
    if (t < 512) nh[t] = 0;
    __syncthreads();
    for (int i = s0 + t; i < s1; i += 1024)
        atomicAdd(&nh[sd_st[i] & 511], 1);
    __syncthreads();
    if (t < 512) ns[t] = nh[t];
    __syncthreads();
    for (int o = 1; o < 512; o <<= 1) {
        int add = 0;
        if (t < 512 && t >= o) add = ns[t - o];
        __syncthreads();
        if (t < 512) ns[t] += add;
        __syncthreads();
    }
    int node0 = k << 9;
    if (t < 512) {
        int start = s0 + ns[t] - nh[t];   // exclusive
        if (node0 + t < n) rp[node0 + t] = start;
        nh[t] = start;                    // becomes cursor
    }
    __syncthreads();
    float c00 = consts[0], c01 = consts[1];
    float c10 = consts[2], c11 = consts[3];
    float c20 = consts[4], c21 = consts[5];
    for (int i = s0 + t; i < s1; i += 1024) {
        unsigned int sdv = sd_st[i];
        unsigned int fv = fh_st[i];
        int dloc = sdv & 511;
        int src = sdv >> 9;
        __half2 hh = *reinterpret_cast<__half2*>(&fv);
        float f0 = __low2float(hh), f1 = __high2float(hh);
        int pos = atomicAdd(&nh[dloc], 1);
        srcs[pos] = src;
        aed0[pos] = f0 * c00 + f1 * c01;
        aed1[pos] = f0 * c10 + f1 * c11;
        aed2[pos] = f0 * c20 + f1 * c21;
    }
}

template <int K>
__global__ void k_hproj(const float* __restrict__ x, const float* __restrict__ W,
                        const float* __restrict__ as_, const float* __restrict__ ad_,
                        float* __restrict__ h, float* __restrict__ asrc,
                        float* __restrict__ adst, int n) {
    __shared__ float sW[K * 32];
    for (int i = threadIdx.x; i < K * 32; i += 256) sW[i] = W[i];
    __syncthreads();
    int node = blockIdx.x * 8 + (threadIdx.x >> 5);
    int j = threadIdx.x & 31;
    if (node >= n) return;
    const float* xr = x + (size_t)node * K;
    float acc = 0.f;
#pragma unroll
    for (int k = 0; k < K; ++k) acc += xr[k] * sW[k * 32 + j];
    h[(size_t)node * 32 + j] = acc;
    float r1 = acc * as_[j], r2 = acc * ad_[j];
    for (int off = 16; off > 0; off >>= 1) {
        r1 += __shfl_xor(r1, off, 32);
        r2 += __shfl_xor(r2, off, 32);
    }
    if (j == 0) { asrc[node] = r1; adst[node] = r2; }
}

// Fused edge-softmax + aggregation. One 32-lane group per dst node.
__global__ void k_agg(const int* __restrict__ rp, const int* __restrict__ srcs,
                      const float* __restrict__ aed, const float* __restrict__ asrc,
                      const float* __restrict__ adst, const float* __restrict__ h,
                      const float* __restrict__ bb, float* __restrict__ xout, int n) {
    int node = blockIdx.x * 8 + (threadIdx.x >> 5);
    int j = threadIdx.x & 31;
    if (node >= n) return;
    int r0 = rp[node], r1 = rp[node + 1];
    float adn = adst[node];
    float acc = 0.f, psum = 0.f;
    for (int c = r0; c < r1; c += 32) {
        int i = c + j;
        float pe = 0.f; int s = 0;
        if (i < r1) {
            s = srcs[i];
            float lg = asrc[s] + adn + aed[i];
            lg = lg > 0.f ? lg : 0.2f * lg;
            pe = __expf(lg);
        }
        psum += pe;
        int cnt = min(32, r1 - c);
        int t = 0;
        for (; t + 4 <= cnt; t += 4) {
            int s0 = __shfl(s, t, 32), s1 = __shfl(s, t + 1, 32);
            int s2 = __shfl(s, t + 2, 32), s3 = __shfl(s, t + 3, 32);
            float p0 = __shfl(pe, t, 32), p1 = __shfl(pe, t + 1, 32);
            float p2 = __shfl(pe, t + 2, 32), p3 = __shfl(pe, t + 3, 32);
            float h0 = h[(size_t)s0 * 32 + j];
            float h1 = h[(size_t)s1 * 32 + j];
            float h2 = h[(size_t)s2 * 32 + j];
            float h3 = h[(size_t)s3 * 32 + j];
            acc += p0 * h0; acc += p1 * h1; acc += p2 * h2; acc += p3 * h3;
        }
        for (; t < cnt; ++t) {
            int st = __shfl(s, t, 32);
            float pt = __shfl(pe, t, 32);
            acc += pt * h[(size_t)st * 32 + j];
        }
    }
    for (int off = 16; off > 0; off >>= 1) psum += __shfl_xor(psum, off, 32);
    xout[(size_t)node * 32 + j] = acc / (psum + 1e-16f) + bb[j];
}

__global__ void k_bounds(const int* __restrict__ batch, int* __restrict__ bounds,
                         int n, int g) {
    int t = blockIdx.x * 256 + threadIdx.x;
    if (t > g) return;
    if (t == g) { bounds[g] = n; return; }
    int lo = 0, hi = n;
    while (lo < hi) {
        int mid = (lo + hi) >> 1;
        if (batch[mid] < t) lo = mid + 1; else hi = mid;
    }
    bounds[t] = lo;
}

// out[g] = (1/cnt_g) * sum_{n in g} (x_cat[n] . W_l3) + b  -- commuted readout.
__global__ void k_dot(const float* __restrict__ x1, const float* __restrict__ x2,
                      const float* __restrict__ x3, const int* __restrict__ batch,
                      const float* __restrict__ Wl3, float* __restrict__ gsum, int n) {
    int node = blockIdx.x * 8 + (threadIdx.x >> 5);
    int j = threadIdx.x & 31;
    if (node >= n) return;
    size_t o = (size_t)node * 32 + j;
    float v = x1[o] * Wl3[j] + x2[o] * Wl3[32 + j] + x3[o] * Wl3[64 + j];
    for (int off = 16; off > 0; off >>= 1) v += __shfl_xor(v, off, 32);
    if (j == 0) atomicAdd(gsum + (size_t)batch[node] * 32 + (blockIdx.x & 31), v);
}

__global__ void k_out(const float* __restrict__ gsum, const int* __restrict__ bounds,
                      const float* __restrict__ bl3, float* __restrict__ out, int g) {
    int t = threadIdx.x;
    if (t >= g) return;
    float acc = 0.f;
    for (int k = 0; k < 32; ++k) acc += gsum[(size_t)t * 32 + k];
    float cnt = (float)(bounds[t + 1] - bounds[t]);
    out[t] = acc / fmaxf(cnt, 1.f) + bl3[0];
}

extern "C" void kernel_launch(void* const* d_in, const int* in_sizes, int n_in,
                              void* d_out, int out_size, void* d_ws, size_t ws_size,
                              hipStream_t stream) {
    (void)n_in; (void)out_size; (void)ws_size;
    const float* nf    = (const float*)d_in[0];
    const int*   ei    = (const int*)d_in[1];
    const float* ea    = (const float*)d_in[2];
    const int*   batch = (const int*)d_in[3];
    const float* W_ne  = (const float*)d_in[4];
    const float* b_ne  = (const float*)d_in[5];
    const float* W_ee  = (const float*)d_in[6];
    const float* b_ee  = (const float*)d_in[7];
    const float* W_l3  = (const float*)d_in[8];
    const float* b_l3  = (const float*)d_in[9];
    const float *Wl[3], *asl[3], *adl[3], *Wel[3], *ael[3], *bbl[3];
    for (int l = 0; l < 3; ++l) {
        Wl[l]  = (const float*)d_in[10 + 6 * l];
        asl[l] = (const float*)d_in[11 + 6 * l];
        adl[l] = (const float*)d_in[12 + 6 * l];
        Wel[l] = (const float*)d_in[13 + 6 * l];
        ael[l] = (const float*)d_in[14 + 6 * l];
        bbl[l] = (const float*)d_in[15 + 6 * l];
    }

    const int n  = in_sizes[3];        // 100000
    const int e  = in_sizes[2] / 3;    // 1600000
    const int ep = e + n;
    const int* ei0 = ei;
    const int* ei1 = ei + e;
    const int nbuck = (n + 511) >> 9;  // 196

    char* w = (char*)d_ws;
    size_t off = 0;
    auto alloc = [&](size_t b) { size_t o = off; off = (off + b + 255) & ~(size_t)255; return o; };
    float*        x0     = (float*)(w + alloc((size_t)n * 16 * 4));
    float*        x1     = (float*)(w + alloc((size_t)n * 32 * 4));
    float*        x2     = (float*)(w + alloc((size_t)n * 32 * 4));
    float*        x3     = (float*)(w + alloc((size_t)n * 32 * 4));
    float*        h      = (float*)(w + alloc((size_t)n * 32 * 4));
    float*        asrc   = (float*)(w + alloc((size_t)n * 4));
    float*        adst   = (float*)(w + alloc((size_t)n * 4));
    unsigned int* sd_st  = (unsigned int*)(w + alloc((size_t)ep * 4));
    unsigned int* fh_st  = (unsigned int*)(w + alloc((size_t)ep * 4));
    int*          srcs   = (int*)(w + alloc((size_t)ep * 4));
    float*        aed0   = (float*)(w + alloc((size_t)ep * 4));
    float*        aed1   = (float*)(w + alloc((size_t)ep * 4));
    float*        aed2   = (float*)(w + alloc((size_t)ep * 4));
    int*          rp     = (int*)(w + alloc((size_t)(n + 1) * 4));
    int*          bcnt   = (int*)(w + alloc(NBUCK_MAX * 4));
    int*          bbase  = (int*)(w + alloc((NBUCK_MAX + 1) * 4));
    int*          bcur   = (int*)(w + alloc(NBUCK_MAX * 4));
    float2*       partial= (float2*)(w + alloc((size_t)8192 * 8));
    float*        consts = (float*)(w + alloc(256));
    int*          bounds = (int*)(w + alloc(129 * 4));
    float*        gsum   = (float*)(w + alloc((size_t)128 * 32 * 4));

    hipMemsetAsync(bcnt, 0, NBUCK_MAX * 4, stream);
    hipMemsetAsync(gsum, 0, (size_t)128 * 32 * 4, stream);

    int e4 = e >> 2;
    int nbe = (e4 + 255) / 256;
    int nw  = nbe * 4;
    int nbs = (ep + 4095) / 4096;

    k_node_enc<<<(n * 16 + 255) / 256, 256, 0, stream>>>(nf, W_ne, b_ne, x0, n);
    k_colsum<<<nbe, 256, 0, stream>>>((const float4*)ea, W_ee, b_ee, partial, e);
    k_consts<<<1, 256, 0, stream>>>(Wel[0], ael[0], Wel[1], ael[1], Wel[2], ael[2],
                                    partial, nw, 1.0f / (float)e, consts);
    k_hist<<<nbs, 256, 0, stream>>>(ei1, bcnt, e, ep);
    k_bbase<<<1, 256, 0, stream>>>(bcnt, bbase, bcur, nbuck, ep, rp, n);
    k_binB<<<nbs, 256, 0, stream>>>(ei0, ei1, ea, W_ee, b_ee, consts,
                                    bcur, sd_st, fh_st, e, ep);
    k_binC<<<nbuck, 1024, 0, stream>>>(sd_st, fh_st, bbase, consts,
                                       rp, srcs, aed0, aed1, aed2, n);
    k_bounds<<<1, 256, 0, stream>>>(batch, bounds, n, 128);

    const float* xin = x0;
    float* xo[3] = {x1, x2, x3};
    const float* aeds[3] = {aed0, aed1, aed2};
    for (int l = 0; l < 3; ++l) {
        if (l == 0)
            k_hproj<16><<<(n + 7) / 8, 256, 0, stream>>>(xin, Wl[l], asl[l], adl[l],
                                                         h, asrc, adst, n);
        else
            k_hproj<32><<<(n + 7) / 8, 256, 0, stream>>>(xin, Wl[l], asl[l], adl[l],
                                                         h, asrc, adst, n);
        k_agg<<<(n + 7) / 8, 256, 0, stream>>>(rp, srcs, aeds[l], asrc, adst,
                                               h, bbl[l], xo[l], n);
        xin = xo[l];
    }
    k_dot<<<(n + 7) / 8, 256, 0, stream>>>(x1, x2, x3, batch, W_l3, gsum, n);
    k_out<<<1, 128, 0, stream>>>(gsum, bounds, b_l3, (float*)d_out, 128);
}

// Round 6
// 414.630 us; speedup vs baseline: 1.7395x; 1.1629x over previous
//
#include <hip/hip_runtime.h>
#include <hip/hip_fp16.h>

// ---------------------------------------------------------------------------
// 3-layer GAT (heads=1) forward. N=100000, E=1600000, Ep=E+N, G=128,
// ND=16, ED=2, H=32.
// R6: phase-C scatter moved into LDS (global writes now fully coalesced);
// one packed uint2 {src, half2(f0,f1)} per edge replaces srcs+aed0/1/2
// (k_agg reconstructs per-layer logit scalar inline); 256-node buckets.
// R5 lesson: global scatter within L2-thrashed regions = ~10x write
// amplification (264MB for 27MB). Scatter in LDS; stream out coalesced.
// ---------------------------------------------------------------------------

#define NBUCK_SHIFT 8
#define NBUCK_MAX 512
#define CAP 6144   // max staged edges per 256-node bucket (mean ~4350, max ~4650)

__global__ void k_node_enc(const float* __restrict__ nf, const float* __restrict__ W,
                           const float* __restrict__ b, float* __restrict__ x, int n) {
    int gid = blockIdx.x * 256 + threadIdx.x;
    if (gid >= n * 16) return;
    int node = gid >> 4, j = gid & 15;
    const float* xr = nf + node * 9;
    float acc = b[j];
#pragma unroll
    for (int k = 0; k < 9; ++k) acc += xr[k] * W[k * 16 + j];
    x[gid] = acc;
}

// Column sums of ef = ea@W_ee + b_ee (self-loop mean fill) without
// materializing ef. Per-wave partial to a unique slot (no atomics).
__global__ void k_colsum(const float4* __restrict__ ea4, const float* __restrict__ W,
                         const float* __restrict__ b, float2* __restrict__ partial, int e) {
    int tid = blockIdx.x * 256 + threadIdx.x;
    int e4 = e >> 2;
    float s0 = 0.f, s1 = 0.f;
    if (tid < e4) {
        float4 q0 = ea4[tid * 3], q1 = ea4[tid * 3 + 1], q2 = ea4[tid * 3 + 2];
        float a = q0.x + q0.w + q1.z + q2.y;
        float b2 = q0.y + q1.x + q1.w + q2.z;
        float c = q0.z + q1.y + q2.x + q2.w;
        s0 = a * W[0] + b2 * W[2] + c * W[4] + 4.f * b[0];
        s1 = a * W[1] + b2 * W[3] + c * W[5] + 4.f * b[1];
    }
#pragma unroll
    for (int off = 32; off > 0; off >>= 1) {
        s0 += __shfl_xor(s0, off, 64);
        s1 += __shfl_xor(s1, off, 64);
    }
    if ((threadIdx.x & 63) == 0)
        partial[(blockIdx.x << 2) + (threadIdx.x >> 6)] = make_float2(s0, s1);
}

// consts: [0..5]=(We@ae) per layer, [12..13]=self-loop mean fill
__global__ void k_consts(const float* __restrict__ We0, const float* __restrict__ ae0,
                         const float* __restrict__ We1, const float* __restrict__ ae1,
                         const float* __restrict__ We2, const float* __restrict__ ae2,
                         const float2* __restrict__ partial, int nw, float einv,
                         float* __restrict__ consts) {
    __shared__ float r0[256], r1[256];
    int t = threadIdx.x;
    float m0 = 0.f, m1 = 0.f;
    for (int i = t; i < nw; i += 256) {
        float2 v = partial[i];
        m0 += v.x; m1 += v.y;
    }
    r0[t] = m0; r1[t] = m1;
    __syncthreads();
    for (int o = 128; o > 0; o >>= 1) {
        if (t < o) { r0[t] += r0[t + o]; r1[t] += r1[t + o]; }
        __syncthreads();
    }
    if (t == 0) {
        consts[12] = r0[0] * einv;
        consts[13] = r1[0] * einv;
        const float* We[3] = {We0, We1, We2};
        const float* ae[3] = {ae0, ae1, ae2};
        for (int l = 0; l < 3; ++l) {
            float c0 = 0.f, c1 = 0.f;
            for (int j = 0; j < 32; ++j) {
                c0 += We[l][j] * ae[l][j];
                c1 += We[l][32 + j] * ae[l][j];
            }
            consts[l * 2 + 0] = c0;
            consts[l * 2 + 1] = c1;
        }
    }
}

// Phase A: bucket histogram (bucket = dst>>8). 4096 edges/block.
__global__ void k_hist(const int* __restrict__ ei1, int* __restrict__ bucket_cnt,
                       int e, int ep) {
    __shared__ int lh[NBUCK_MAX];
    int t = threadIdx.x;
    lh[t] = 0; lh[t + 256] = 0;
    __syncthreads();
    int base = blockIdx.x * 4096;
#pragma unroll
    for (int i = 0; i < 16; ++i) {
        int gid = base + i * 256 + t;
        if (gid < ep) {
            int d = (gid < e) ? ei1[gid] : gid - e;
            atomicAdd(&lh[d >> NBUCK_SHIFT], 1);
        }
    }
    __syncthreads();
    if (lh[t]) atomicAdd(&bucket_cnt[t], lh[t]);
    if (lh[t + 256]) atomicAdd(&bucket_cnt[t + 256], lh[t + 256]);
}

// Exclusive scan of bucket counts -> bases + cursors.
__global__ void __launch_bounds__(512)
k_bbase(const int* __restrict__ bucket_cnt, int* __restrict__ bucket_base,
        int* __restrict__ bcursor, int nbuck, int ep, int* __restrict__ rp, int n) {
    __shared__ int s[512];
    int t = threadIdx.x;
    int v = (t < nbuck) ? bucket_cnt[t] : 0;
    s[t] = v;
    __syncthreads();
    for (int o = 1; o < 512; o <<= 1) {
        int x = (t >= o) ? s[t - o] : 0;
        __syncthreads();
        s[t] += x;
        __syncthreads();
    }
    int ex = s[t] - v;
    if (t < nbuck) { bucket_base[t] = ex; bcursor[t] = ex; }
    if (t == 0) { bucket_base[nbuck] = ep; rp[n] = ep; }
}

// Phase B: stage edges grouped by bucket; one 8B uint2 {src<<8|dloc, half2}
// per edge; per-(block,bucket) run reservation keeps stores line-local.
__global__ void k_binB(const int* __restrict__ ei0, const int* __restrict__ ei1,
                       const float* __restrict__ ea, const float* __restrict__ We,
                       const float* __restrict__ be, const float* __restrict__ consts,
                       int* __restrict__ bcursor, uint2* __restrict__ st, int e, int ep) {
    __shared__ int lh[NBUCK_MAX], lcur[NBUCK_MAX];
    int t = threadIdx.x;
    lh[t] = 0; lh[t + 256] = 0;
    __syncthreads();
    int base = blockIdx.x * 4096;
    unsigned int sd[16], fh[16];
    int bk[16];
    float w00 = We[0], w10 = We[2], w20 = We[4];
    float w01 = We[1], w11 = We[3], w21 = We[5];
    float b0 = be[0], b1 = be[1];
#pragma unroll
    for (int i = 0; i < 16; ++i) {
        int gid = base + i * 256 + t;
        bk[i] = -1;
        if (gid < ep) {
            int s, d; float f0, f1;
            if (gid < e) {
                s = ei0[gid]; d = ei1[gid];
                const float* r = ea + (size_t)gid * 3;
                float a0 = r[0], a1 = r[1], a2 = r[2];
                f0 = a0 * w00 + a1 * w10 + a2 * w20 + b0;
                f1 = a0 * w01 + a1 * w11 + a2 * w21 + b1;
            } else {
                s = d = gid - e;
                f0 = consts[12]; f1 = consts[13];
            }
            bk[i] = d >> NBUCK_SHIFT;
            sd[i] = ((unsigned int)s << NBUCK_SHIFT) | (unsigned int)(d & 255);
            __half2 hh = __floats2half2_rn(f0, f1);
            fh[i] = *reinterpret_cast<unsigned int*>(&hh);
            atomicAdd(&lh[bk[i]], 1);
        }
    }
    __syncthreads();
    if (lh[t] > 0) lcur[t] = atomicAdd(&bcursor[t], lh[t]);
    if (lh[t + 256] > 0) lcur[t + 256] = atomicAdd(&bcursor[t + 256], lh[t + 256]);
    __syncthreads();
#pragma unroll
    for (int i = 0; i < 16; ++i) {
        if (bk[i] >= 0) {
            int pos = atomicAdd(&lcur[bk[i]], 1);
            st[pos] = make_uint2(sd[i], fh[i]);
        }
    }
}

// Phase C: one 512-thread block per bucket. Pass 1: LDS node-hist (st read 1).
// Scan -> rp coalesced. Pass 2: scatter into LDS-sorted buffer (st read 2),
// then stream out fully coalesced. Global writes: rp + rec only.
__global__ void __launch_bounds__(512)
k_binC(const uint2* __restrict__ st, const int* __restrict__ bucket_base,
       int* __restrict__ rp, uint2* __restrict__ rec, int n) {
    __shared__ int nh[256], ns[256];
    __shared__ uint2 rs[CAP];
    int k = blockIdx.x, t = threadIdx.x;
    int s0 = bucket_base[k], s1 = bucket_base[k + 1];
    int cnt = s1 - s0;
    if (t < 256) nh[t] = 0;
    __syncthreads();
    for (int i = s0 + t; i < s1; i += 512)
        atomicAdd(&nh[st[i].x & 255], 1);
    __syncthreads();
    if (t < 256) ns[t] = nh[t];
    __syncthreads();
    for (int o = 1; o < 256; o <<= 1) {
        int add = 0;
        if (t < 256 && t >= o) add = ns[t - o];
        __syncthreads();
        if (t < 256) ns[t] += add;
        __syncthreads();
    }
    int node0 = k << NBUCK_SHIFT;
    if (t < 256) {
        int startl = ns[t] - nh[t];      // exclusive, bucket-local
        if (node0 + t < n) rp[node0 + t] = s0 + startl;
        nh[t] = startl;                  // becomes local cursor
    }
    __syncthreads();
    for (int i = s0 + t; i < s1; i += 512) {
        uint2 v = st[i];
        int pos = atomicAdd(&nh[v.x & 255], 1);
        uint2 r = make_uint2(v.x >> NBUCK_SHIFT, v.y);
        if (pos < CAP) rs[pos] = r;
        else rec[s0 + pos] = r;          // overflow fallback (never in practice)
    }
    __syncthreads();
    int m = cnt < CAP ? cnt : CAP;
    for (int i = t; i < m; i += 512)
        rec[s0 + i] = rs[i];
}

template <int K>
__global__ void k_hproj(const float* __restrict__ x, const float* __restrict__ W,
                        const float* __restrict__ as_, const float* __restrict__ ad_,
                        float* __restrict__ h, float* __restrict__ asrc,
                        float* __restrict__ adst, int n) {
    __shared__ float sW[K * 32];
    for (int i = threadIdx.x; i < K * 32; i += 256) sW[i] = W[i];
    __syncthreads();
    int node = blockIdx.x * 8 + (threadIdx.x >> 5);
    int j = threadIdx.x & 31;
    if (node >= n) return;
    const float* xr = x + (size_t)node * K;
    float acc = 0.f;
#pragma unroll
    for (int k = 0; k < K; ++k) acc += xr[k] * sW[k * 32 + j];
    h[(size_t)node * 32 + j] = acc;
    float r1 = acc * as_[j], r2 = acc * ad_[j];
    for (int off = 16; off > 0; off >>= 1) {
        r1 += __shfl_xor(r1, off, 32);
        r2 += __shfl_xor(r2, off, 32);
    }
    if (j == 0) { asrc[node] = r1; adst[node] = r2; }
}

// Fused edge-softmax + aggregation. One 32-lane group per dst node.
// rec = {src, half2(f0,f1)}; per-layer logit scalar rebuilt inline.
__global__ void k_agg(const int* __restrict__ rp, const uint2* __restrict__ rec,
                      const float* __restrict__ asrc, const float* __restrict__ adst,
                      const float* __restrict__ consts, const float* __restrict__ h,
                      const float* __restrict__ bb, float* __restrict__ xout,
                      int n, int layer) {
    int node = blockIdx.x * 8 + (threadIdx.x >> 5);
    int j = threadIdx.x & 31;
    if (node >= n) return;
    float c0 = consts[layer * 2], c1 = consts[layer * 2 + 1];
    int r0 = rp[node], r1 = rp[node + 1];
    float adn = adst[node];
    float acc = 0.f, psum = 0.f;
    for (int c = r0; c < r1; c += 32) {
        int i = c + j;
        float pe = 0.f; int s = 0;
        if (i < r1) {
            uint2 v = rec[i];
            s = (int)v.x;
            __half2 hh = *reinterpret_cast<__half2*>(&v.y);
            float lg = asrc[s] + adn + __low2float(hh) * c0 + __high2float(hh) * c1;
            lg = lg > 0.f ? lg : 0.2f * lg;
            pe = __expf(lg);
        }
        psum += pe;
        int cnt = min(32, r1 - c);
        int t = 0;
        for (; t + 4 <= cnt; t += 4) {
            int s0 = __shfl(s, t, 32), s1 = __shfl(s, t + 1, 32);
            int s2 = __shfl(s, t + 2, 32), s3 = __shfl(s, t + 3, 32);
            float p0 = __shfl(pe, t, 32), p1 = __shfl(pe, t + 1, 32);
            float p2 = __shfl(pe, t + 2, 32), p3 = __shfl(pe, t + 3, 32);
            float h0 = h[(size_t)s0 * 32 + j];
            float h1 = h[(size_t)s1 * 32 + j];
            float h2 = h[(size_t)s2 * 32 + j];
            float h3 = h[(size_t)s3 * 32 + j];
            acc += p0 * h0; acc += p1 * h1; acc += p2 * h2; acc += p3 * h3;
        }
        for (; t < cnt; ++t) {
            int st2 = __shfl(s, t, 32);
            float pt = __shfl(pe, t, 32);
            acc += pt * h[(size_t)st2 * 32 + j];
        }
    }
    for (int off = 16; off > 0; off >>= 1) psum += __shfl_xor(psum, off, 32);
    xout[(size_t)node * 32 + j] = acc / (psum + 1e-16f) + bb[j];
}

__global__ void k_bounds(const int* __restrict__ batch, int* __restrict__ bounds,
                         int n, int g) {
    int t = blockIdx.x * 256 + threadIdx.x;
    if (t > g) return;
    if (t == g) { bounds[g] = n; return; }
    int lo = 0, hi = n;
    while (lo < hi) {
        int mid = (lo + hi) >> 1;
        if (batch[mid] < t) lo = mid + 1; else hi = mid;
    }
    bounds[t] = lo;
}

// out[g] = (1/cnt_g) * sum_{n in g} (x_cat[n] . W_l3) + b  -- commuted readout.
__global__ void k_dot(const float* __restrict__ x1, const float* __restrict__ x2,
                      const float* __restrict__ x3, const int* __restrict__ batch,
                      const float* __restrict__ Wl3, float* __restrict__ gsum, int n) {
    int node = blockIdx.x * 8 + (threadIdx.x >> 5);
    int j = threadIdx.x & 31;
    if (node >= n) return;
    size_t o = (size_t)node * 32 + j;
    float v = x1[o] * Wl3[j] + x2[o] * Wl3[32 + j] + x3[o] * Wl3[64 + j];
    for (int off = 16; off > 0; off >>= 1) v += __shfl_xor(v, off, 32);
    if (j == 0) atomicAdd(gsum + (size_t)batch[node] * 32 + (blockIdx.x & 31), v);
}

__global__ void k_out(const float* __restrict__ gsum, const int* __restrict__ bounds,
                      const float* __restrict__ bl3, float* __restrict__ out, int g) {
    int t = threadIdx.x;
    if (t >= g) return;
    float acc = 0.f;
    for (int k = 0; k < 32; ++k) acc += gsum[(size_t)t * 32 + k];
    float cnt = (float)(bounds[t + 1] - bounds[t]);
    out[t] = acc / fmaxf(cnt, 1.f) + bl3[0];
}

extern "C" void kernel_launch(void* const* d_in, const int* in_sizes, int n_in,
                              void* d_out, int out_size, void* d_ws, size_t ws_size,
                              hipStream_t stream) {
    (void)n_in; (void)out_size; (void)ws_size;
    const float* nf    = (const float*)d_in[0];
    const int*   ei    = (const int*)d_in[1];
    const float* ea    = (const float*)d_in[2];
    const int*   batch = (const int*)d_in[3];
    const float* W_ne  = (const float*)d_in[4];
    const float* b_ne  = (const float*)d_in[5];
    const float* W_ee  = (const float*)d_in[6];
    const float* b_ee  = (const float*)d_in[7];
    const float* W_l3  = (const float*)d_in[8];
    const float* b_l3  = (const float*)d_in[9];
    const float *Wl[3], *asl[3], *adl[3], *Wel[3], *ael[3], *bbl[3];
    for (int l = 0; l < 3; ++l) {
        Wl[l]  = (const float*)d_in[10 + 6 * l];
        asl[l] = (const float*)d_in[11 + 6 * l];
        adl[l] = (const float*)d_in[12 + 6 * l];
        Wel[l] = (const float*)d_in[13 + 6 * l];
        ael[l] = (const float*)d_in[14 + 6 * l];
        bbl[l] = (const float*)d_in[15 + 6 * l];
    }

    const int n  = in_sizes[3];        // 100000
    const int e  = in_sizes[2] / 3;    // 1600000
    const int ep = e + n;
    const int* ei0 = ei;
    const int* ei1 = ei + e;
    const int nbuck = (n + 255) >> NBUCK_SHIFT;   // 391

    char* w = (char*)d_ws;
    size_t off = 0;
    auto alloc = [&](size_t b) { size_t o = off; off = (off + b + 255) & ~(size_t)255; return o; };
    float*  x0      = (float*)(w + alloc((size_t)n * 16 * 4));
    float*  x1      = (float*)(w + alloc((size_t)n * 32 * 4));
    float*  x2      = (float*)(w + alloc((size_t)n * 32 * 4));
    float*  x3      = (float*)(w + alloc((size_t)n * 32 * 4));
    float*  h       = (float*)(w + alloc((size_t)n * 32 * 4));
    float*  asrc    = (float*)(w + alloc((size_t)n * 4));
    float*  adst    = (float*)(w + alloc((size_t)n * 4));
    uint2*  st      = (uint2*)(w + alloc((size_t)ep * 8));
    uint2*  rec     = (uint2*)(w + alloc((size_t)ep * 8));
    int*    rp      = (int*)(w + alloc((size_t)(n + 1) * 4));
    int*    bcnt    = (int*)(w + alloc(NBUCK_MAX * 4));
    int*    bbase   = (int*)(w + alloc((NBUCK_MAX + 1) * 4));
    int*    bcur    = (int*)(w + alloc(NBUCK_MAX * 4));
    float2* partial = (float2*)(w + alloc((size_t)8192 * 8));
    float*  consts  = (float*)(w + alloc(256));
    int*    bounds  = (int*)(w + alloc(129 * 4));
    float*  gsum    = (float*)(w + alloc((size_t)128 * 32 * 4));

    hipMemsetAsync(bcnt, 0, NBUCK_MAX * 4, stream);
    hipMemsetAsync(gsum, 0, (size_t)128 * 32 * 4, stream);

    int e4 = e >> 2;
    int nbe = (e4 + 255) / 256;
    int nw  = nbe * 4;
    int nbs = (ep + 4095) / 4096;

    k_node_enc<<<(n * 16 + 255) / 256, 256, 0, stream>>>(nf, W_ne, b_ne, x0, n);
    k_colsum<<<nbe, 256, 0, stream>>>((const float4*)ea, W_ee, b_ee, partial, e);
    k_consts<<<1, 256, 0, stream>>>(Wel[0], ael[0], Wel[1], ael[1], Wel[2], ael[2],
                                    partial, nw, 1.0f / (float)e, consts);
    k_hist<<<nbs, 256, 0, stream>>>(ei1, bcnt, e, ep);
    k_bbase<<<1, 512, 0, stream>>>(bcnt, bbase, bcur, nbuck, ep, rp, n);
    k_binB<<<nbs, 256, 0, stream>>>(ei0, ei1, ea, W_ee, b_ee, consts, bcur, st, e, ep);
    k_binC<<<nbuck, 512, 0, stream>>>(st, bbase, rp, rec, n);
    k_bounds<<<1, 256, 0, stream>>>(batch, bounds, n, 128);

    const float* xin = x0;
    float* xo[3] = {x1, x2, x3};
    for (int l = 0; l < 3; ++l) {
        if (l == 0)
            k_hproj<16><<<(n + 7) / 8, 256, 0, stream>>>(xin, Wl[l], asl[l], adl[l],
                                                         h, asrc, adst, n);
        else
            k_hproj<32><<<(n + 7) / 8, 256, 0, stream>>>(xin, Wl[l], asl[l], adl[l],
                                                         h, asrc, adst, n);
        k_agg<<<(n + 7) / 8, 256, 0, stream>>>(rp, rec, asrc, adst, consts,
                                               h, bbl[l], xo[l], n, l);
        xin = xo[l];
    }
    k_dot<<<(n + 7) / 8, 256, 0, stream>>>(x1, x2, x3, batch, W_l3, gsum, n);
    k_out<<<1, 128, 0, stream>>>(gsum, bounds, b_l3, (float*)d_out, 128);
}